// Round 2
// baseline (111.576 us; speedup 1.0000x reference)
//
#include <hip/hip_runtime.h>

// Affine-grid bilinear sampler (spatial transformer), fp32.
// B=16, H=512, W=512, C=16. Each thread handles 4 (pixel, float4-group) items
// strided by N/4 items = 4 batches: same (xo,yo) -> grid math computed once,
// 16 independent gather loads in flight for latency hiding.

constexpr int B_ = 16;
constexpr int H_ = 512;
constexpr int W_ = 512;
constexpr int C_ = 16;
constexpr int ITEMS   = B_ * H_ * W_ * (C_ / 4);   // 16,777,216
constexpr int NTHREAD = ITEMS / 4;                 // 4,194,304
constexpr int PIX_STRIDE = NTHREAD / 4;            // 1,048,576 pixels = 4 batches

__global__ __launch_bounds__(256) void spatial_sample_kernel(
    const float* __restrict__ img,    // [B,H,W,C]
    const float* __restrict__ theta,  // [B,2,3]
    float* __restrict__ out)          // [B,H,W,C]
{
    const int tid = blockIdx.x * blockDim.x + threadIdx.x;
    const int cg  = tid & 3;          // float4 group within 16 channels
    const int pix = tid >> 2;         // pixel id within first 4 batches' range
    const int xo  = pix & (W_ - 1);
    const int yo  = (pix >> 9) & (H_ - 1);
    const int b0  = pix >> 18;        // 0..3

    // normalized grid coords (match np.linspace(-1,1,N))
    const float xn = fmaf((float)xo, 2.0f / (float)(W_ - 1), -1.0f);
    const float yn = fmaf((float)yo, 2.0f / (float)(H_ - 1), -1.0f);

    const int cgo = cg * 4;

#pragma unroll
    for (int k = 0; k < 4; ++k) {
        const int b = b0 + 4 * k;                       // wave-uniform
        const int bu = __builtin_amdgcn_readfirstlane(b);
        const float* th = theta + bu * 6;

        const float gx = fmaf(th[0], xn, fmaf(th[1], yn, th[2]));
        const float gy = fmaf(th[3], xn, fmaf(th[4], yn, th[5]));

        const float x = 0.5f * ((gx + 1.0f) * (float)(W_ - 2));
        const float y = 0.5f * ((gy + 1.0f) * (float)(H_ - 2));

        int x0 = (int)floorf(x);
        int y0 = (int)floorf(y);
        x0 = min(max(x0, 0), W_ - 1);
        y0 = min(max(y0, 0), H_ - 1);
        const int x1 = min(x0 + 1, W_ - 1);
        const int y1 = min(y0 + 1, H_ - 1);

        const float x0f = (float)x0, x1f = (float)x1;
        const float y0f = (float)y0, y1f = (float)y1;
        const float wa = (x1f - x) * (y1f - y);
        const float wb = (x1f - x) * (y - y0f);
        const float wc = (x - x0f) * (y1f - y);
        const float wd = (x - x0f) * (y - y0f);

        const size_t base_b = (size_t)b * (H_ * W_ * C_);
        const float* pa = img + base_b + ((size_t)y0 * W_ + x0) * C_ + cgo;
        const float* pb = img + base_b + ((size_t)y1 * W_ + x0) * C_ + cgo;
        const float* pc = img + base_b + ((size_t)y0 * W_ + x1) * C_ + cgo;
        const float* pd = img + base_b + ((size_t)y1 * W_ + x1) * C_ + cgo;

        const float4 Ia = *reinterpret_cast<const float4*>(pa);
        const float4 Ib = *reinterpret_cast<const float4*>(pb);
        const float4 Ic = *reinterpret_cast<const float4*>(pc);
        const float4 Id = *reinterpret_cast<const float4*>(pd);

        float4 r;
        r.x = wa * Ia.x + wb * Ib.x + wc * Ic.x + wd * Id.x;
        r.y = wa * Ia.y + wb * Ib.y + wc * Ic.y + wd * Id.y;
        r.z = wa * Ia.z + wb * Ib.z + wc * Ic.z + wd * Id.z;
        r.w = wa * Ia.w + wb * Ib.w + wc * Ic.w + wd * Id.w;

        *reinterpret_cast<float4*>(
            out + ((size_t)pix + (size_t)k * PIX_STRIDE) * C_ + cgo) = r;
    }
}

extern "C" void kernel_launch(void* const* d_in, const int* in_sizes, int n_in,
                              void* d_out, int out_size, void* d_ws, size_t ws_size,
                              hipStream_t stream) {
    const float* img   = (const float*)d_in[0];
    const float* theta = (const float*)d_in[1];
    float* out = (float*)d_out;

    const int block = 256;
    const int grid  = NTHREAD / block;   // 16,384
    spatial_sample_kernel<<<grid, block, 0, stream>>>(img, theta, out);
}

// Round 4
// 75.612 us; speedup vs baseline: 1.4756x; 1.4756x over previous
//
#include <hip/hip_runtime.h>

// Affine-grid bilinear sampler (spatial transformer), fp32.
// B=16, H=512, W=512, C=16. One thread per (pixel, float4 channel group).
// Round-1 structure (best access pattern) + nontemporal stores (keep L2 for
// img gather reuse) + XCD-aware block swizzle (contiguous grid chunk per XCD).

constexpr int B_ = 16;
constexpr int H_ = 512;
constexpr int W_ = 512;
constexpr int C_ = 16;
constexpr int NXCD = 8;

typedef float vfloat4 __attribute__((ext_vector_type(4)));  // native clang vector

__global__ __launch_bounds__(256) void spatial_sample_kernel(
    const float* __restrict__ img,    // [B,H,W,C]
    const float* __restrict__ theta,  // [B,2,3]
    float* __restrict__ out)          // [B,H,W,C]
{
    // XCD-aware swizzle: gridDim.x % 8 == 0, bijective chunked remap.
    const int nwg  = gridDim.x;
    const int cpx  = nwg / NXCD;                    // chunks per XCD
    const int bid  = blockIdx.x;
    const int sbid = (bid % NXCD) * cpx + bid / NXCD;

    const int tid = sbid * blockDim.x + threadIdx.x;
    const int cg  = tid & 3;          // which float4 of the 16 channels
    const int pix = tid >> 2;
    const int xo  = pix & (W_ - 1);
    const int yo  = (pix >> 9) & (H_ - 1);
    const int b   = pix >> 18;

    // normalized grid coords (match np.linspace(-1,1,N): start + i*step)
    const float xn = fmaf((float)xo, 2.0f / (float)(W_ - 1), -1.0f);
    const float yn = fmaf((float)yo, 2.0f / (float)(H_ - 1), -1.0f);

    const float* th = theta + b * 6;
    const float gx = fmaf(th[0], xn, fmaf(th[1], yn, th[2]));
    const float gy = fmaf(th[3], xn, fmaf(th[4], yn, th[5]));

    // x = 0.5*((gx+1)*(max_x-1)), max_x = W-1
    const float x = 0.5f * ((gx + 1.0f) * (float)(W_ - 2));
    const float y = 0.5f * ((gy + 1.0f) * (float)(H_ - 2));

    int x0 = (int)floorf(x);
    int y0 = (int)floorf(y);
    x0 = min(max(x0, 0), W_ - 1);
    y0 = min(max(y0, 0), H_ - 1);
    const int x1 = min(x0 + 1, W_ - 1);
    const int y1 = min(y0 + 1, H_ - 1);

    const float x0f = (float)x0, x1f = (float)x1;
    const float y0f = (float)y0, y1f = (float)y1;
    const float wa = (x1f - x) * (y1f - y);
    const float wb = (x1f - x) * (y - y0f);
    const float wc = (x - x0f) * (y1f - y);
    const float wd = (x - x0f) * (y - y0f);

    const size_t base_b = (size_t)b * H_ * W_ * C_;
    const size_t ia = base_b + ((size_t)y0 * W_ + x0) * C_ + cg * 4;
    const size_t ib = base_b + ((size_t)y1 * W_ + x0) * C_ + cg * 4;
    const size_t ic = base_b + ((size_t)y0 * W_ + x1) * C_ + cg * 4;
    const size_t id = base_b + ((size_t)y1 * W_ + x1) * C_ + cg * 4;

    const vfloat4 Ia = *reinterpret_cast<const vfloat4*>(img + ia);
    const vfloat4 Ib = *reinterpret_cast<const vfloat4*>(img + ib);
    const vfloat4 Ic = *reinterpret_cast<const vfloat4*>(img + ic);
    const vfloat4 Id = *reinterpret_cast<const vfloat4*>(img + id);

    const vfloat4 r = wa * Ia + wb * Ib + wc * Ic + wd * Id;

    __builtin_nontemporal_store(
        r, reinterpret_cast<vfloat4*>(out + (size_t)pix * C_ + cg * 4));
}

extern "C" void kernel_launch(void* const* d_in, const int* in_sizes, int n_in,
                              void* d_out, int out_size, void* d_ws, size_t ws_size,
                              hipStream_t stream) {
    const float* img   = (const float*)d_in[0];
    const float* theta = (const float*)d_in[1];
    float* out = (float*)d_out;

    const int total = B_ * H_ * W_ * (C_ / 4);   // 16,777,216
    const int block = 256;
    const int grid  = total / block;             // 65,536 (% 8 == 0)
    spatial_sample_kernel<<<grid, block, 0, stream>>>(img, theta, out);
}

// Round 5
// 75.611 us; speedup vs baseline: 1.4757x; 1.0000x over previous
//
#include <hip/hip_runtime.h>

// Affine-grid bilinear sampler (spatial transformer), fp32.
// B=16, H=512, W=512, C=16. Two (pixel, float4-group) items per thread,
// 256 items (1 KB) apart in the SAME row: stores stay perfectly coalesced,
// 8 gather loads in flight per thread. NT stores + XCD-chunked swizzle.

constexpr int B_ = 16;
constexpr int H_ = 512;
constexpr int W_ = 512;
constexpr int C_ = 16;
constexpr int NXCD = 8;

typedef float vfloat4 __attribute__((ext_vector_type(4)));

__global__ __launch_bounds__(256) void spatial_sample_kernel(
    const float* __restrict__ img,    // [B,H,W,C]
    const float* __restrict__ theta,  // [B,2,3]
    float* __restrict__ out)          // [B,H,W,C]
{
    // XCD-aware swizzle: gridDim.x % 8 == 0, bijective chunked remap.
    const int nwg  = gridDim.x;
    const int cpx  = nwg / NXCD;
    const int bid  = blockIdx.x;
    const int sbid = (bid % NXCD) * cpx + bid / NXCD;

    // Each block owns 512 consecutive items; thread t handles items
    // base+t and base+256+t (same batch, same row: pixels 64 apart).
    const int item0 = sbid * 512 + threadIdx.x;

    const int cg  = item0 & 3;
    const int pix = item0 >> 2;
    const int xo  = pix & (W_ - 1);
    const int yo  = (pix >> 9) & (H_ - 1);
    const int b   = pix >> 18;

    const float yn = fmaf((float)yo, 2.0f / (float)(H_ - 1), -1.0f);

    const float* th = theta + b * 6;
    const float t0 = th[0], t1 = th[1], t2 = th[2];
    const float t3 = th[3], t4 = th[4], t5 = th[5];
    const float gxy = fmaf(t1, yn, t2);   // gx = t0*xn + gxy
    const float gyy = fmaf(t4, yn, t5);   // gy = t3*xn + gyy

    const size_t base_b = (size_t)b * H_ * W_ * C_;
    const int cgo = cg * 4;

    vfloat4 res[2];
    size_t oidx[2];

#pragma unroll
    for (int k = 0; k < 2; ++k) {
        const int xk = xo + k * 64;                   // second item: +64 pixels, same row
        const float xn = fmaf((float)xk, 2.0f / (float)(W_ - 1), -1.0f);
        const float gx = fmaf(t0, xn, gxy);
        const float gy = fmaf(t3, xn, gyy);

        const float x = 0.5f * ((gx + 1.0f) * (float)(W_ - 2));
        const float y = 0.5f * ((gy + 1.0f) * (float)(H_ - 2));

        int x0 = (int)floorf(x);
        int y0 = (int)floorf(y);
        x0 = min(max(x0, 0), W_ - 1);
        y0 = min(max(y0, 0), H_ - 1);
        const int x1 = min(x0 + 1, W_ - 1);
        const int y1 = min(y0 + 1, H_ - 1);

        const float x0f = (float)x0, x1f = (float)x1;
        const float y0f = (float)y0, y1f = (float)y1;
        const float wa = (x1f - x) * (y1f - y);
        const float wb = (x1f - x) * (y - y0f);
        const float wc = (x - x0f) * (y1f - y);
        const float wd = (x - x0f) * (y - y0f);

        const vfloat4 Ia = *reinterpret_cast<const vfloat4*>(
            img + base_b + ((size_t)y0 * W_ + x0) * C_ + cgo);
        const vfloat4 Ib = *reinterpret_cast<const vfloat4*>(
            img + base_b + ((size_t)y1 * W_ + x0) * C_ + cgo);
        const vfloat4 Ic = *reinterpret_cast<const vfloat4*>(
            img + base_b + ((size_t)y0 * W_ + x1) * C_ + cgo);
        const vfloat4 Id = *reinterpret_cast<const vfloat4*>(
            img + base_b + ((size_t)y1 * W_ + x1) * C_ + cgo);

        res[k] = wa * Ia + wb * Ib + wc * Ic + wd * Id;
        oidx[k] = ((size_t)pix + (size_t)k * 64) * C_ + cgo;
    }

    __builtin_nontemporal_store(res[0], reinterpret_cast<vfloat4*>(out + oidx[0]));
    __builtin_nontemporal_store(res[1], reinterpret_cast<vfloat4*>(out + oidx[1]));
}

extern "C" void kernel_launch(void* const* d_in, const int* in_sizes, int n_in,
                              void* d_out, int out_size, void* d_ws, size_t ws_size,
                              hipStream_t stream) {
    const float* img   = (const float*)d_in[0];
    const float* theta = (const float*)d_in[1];
    float* out = (float*)d_out;

    const int total = B_ * H_ * W_ * (C_ / 4);   // 16,777,216 items
    const int block = 256;
    const int grid  = total / (block * 2);       // 32,768 (% 8 == 0)
    spatial_sample_kernel<<<grid, block, 0, stream>>>(img, theta, out);
}